// Round 2
// baseline (159.776 us; speedup 1.0000x reference)
//
#include <hip/hip_runtime.h>

// SpiralConv conv block: per-channel complex first-order recurrence
//   h[n] = c*h[n-1] + x[n],  h[-1] = last_conv_init[d],  out = Re(h)*x
// with c_d = exp(-exp(lmlg_d)) * e^{i*theta_d}.
// 3-phase chunked parallel scan over L. Chunk count adapts to ws_size —
// round-1 failure was phase1 writing 4 MiB into d_ws unconditionally,
// overflowing the harness scratch and corrupting pristine input copies.

#define L_  4096
#define B_  4
#define D_  1024
#define BD_ (B_ * D_)       // 4096 floats per time step

// ---------------------------------------------------------------- phase 1 ---
// One block per (chunk k, batch b); 256 threads x 4 channels = D.
// Computes chunk summary s = sum_j c^{ch-1-j} x[j]  (recurrence from 0).
__global__ __launch_bounds__(256) void sc_phase1(
    const float* __restrict__ x,
    const float* __restrict__ lmlg,
    const float* __restrict__ theta,
    float2* __restrict__ ws, int ch) {
  const int t  = threadIdx.x;
  const int k  = blockIdx.x / B_;
  const int b  = blockIdx.x % B_;
  const int d0 = t * 4;

  float4 lg = *(const float4*)(lmlg + d0);
  float4 th = *(const float4*)(theta + d0);
  float cr[4], ci[4], sr[4] = {0.f,0.f,0.f,0.f}, si[4] = {0.f,0.f,0.f,0.f};
  {
    float g0 = expf(-expf(lg.x)), g1 = expf(-expf(lg.y));
    float g2 = expf(-expf(lg.z)), g3 = expf(-expf(lg.w));
    cr[0] = g0 * cosf(th.x); ci[0] = g0 * sinf(th.x);
    cr[1] = g1 * cosf(th.y); ci[1] = g1 * sinf(th.y);
    cr[2] = g2 * cosf(th.z); ci[2] = g2 * sinf(th.z);
    cr[3] = g3 * cosf(th.w); ci[3] = g3 * sinf(th.w);
  }

  const float* xp = x + (size_t)k * ch * BD_ + (size_t)b * D_ + d0;
#pragma unroll 4
  for (int j = 0; j < ch; ++j) {
    float4 xv = *(const float4*)(xp + (size_t)j * BD_);
    float xa[4] = {xv.x, xv.y, xv.z, xv.w};
#pragma unroll
    for (int q = 0; q < 4; ++q) {
      float nr = fmaf(cr[q], sr[q], fmaf(-ci[q], si[q], xa[q]));
      float ni = fmaf(cr[q], si[q], ci[q] * sr[q]);
      sr[q] = nr; si[q] = ni;
    }
  }

  float2* wp = ws + (size_t)k * BD_ + (size_t)b * D_ + d0;
  wp[0] = make_float2(sr[0], si[0]);
  wp[1] = make_float2(sr[1], si[1]);
  wp[2] = make_float2(sr[2], si[2]);
  wp[3] = make_float2(sr[3], si[3]);
}

// ---------------------------------------------------------------- phase 2 ---
// One thread per (b,d). Scan chunk summaries with jump factor c^ch.
// In-place: ws[k] (summary) is replaced with the carry INTO chunk k.
__global__ __launch_bounds__(256) void sc_phase2(
    const float* __restrict__ lmlg,
    const float* __restrict__ theta,
    const float* __restrict__ init,
    float2* __restrict__ ws, int nc, float chf) {
  const int idx = blockIdx.x * 256 + threadIdx.x;   // 0..BD_-1 == b*D_+d
  const int d   = idx & (D_ - 1);
  float e  = expf(lmlg[d]);
  float th = theta[d];
  float gC = expf(-e * chf);            // gamma^ch
  float aC = th * chf;
  float Cr = gC * cosf(aC), Ci = gC * sinf(aC);
  float hr = init[d], hi = 0.f;
  for (int k = 0; k < nc; ++k) {
    float2 s = ws[(size_t)k * BD_ + idx];
    ws[(size_t)k * BD_ + idx] = make_float2(hr, hi);
    float nr = fmaf(Cr, hr, fmaf(-Ci, hi, s.x));
    float ni = fmaf(Cr, hi, fmaf(Ci, hr, s.y));
    hr = nr; hi = ni;
  }
}

// ---------------------------------------------------------------- phase 3 ---
// Same mapping as phase 1; seed from carry, emit out = Re(h)*x.
__global__ __launch_bounds__(256) void sc_phase3(
    const float* __restrict__ x,
    const float* __restrict__ lmlg,
    const float* __restrict__ theta,
    const float2* __restrict__ ws,
    float* __restrict__ out, int ch) {
  const int t  = threadIdx.x;
  const int k  = blockIdx.x / B_;
  const int b  = blockIdx.x % B_;
  const int d0 = t * 4;

  float4 lg = *(const float4*)(lmlg + d0);
  float4 th = *(const float4*)(theta + d0);
  float cr[4], ci[4];
  {
    float g0 = expf(-expf(lg.x)), g1 = expf(-expf(lg.y));
    float g2 = expf(-expf(lg.z)), g3 = expf(-expf(lg.w));
    cr[0] = g0 * cosf(th.x); ci[0] = g0 * sinf(th.x);
    cr[1] = g1 * cosf(th.y); ci[1] = g1 * sinf(th.y);
    cr[2] = g2 * cosf(th.z); ci[2] = g2 * sinf(th.z);
    cr[3] = g3 * cosf(th.w); ci[3] = g3 * sinf(th.w);
  }

  const float2* wp = ws + (size_t)k * BD_ + (size_t)b * D_ + d0;
  float hr[4], hi[4];
#pragma unroll
  for (int q = 0; q < 4; ++q) { float2 h = wp[q]; hr[q] = h.x; hi[q] = h.y; }

  const size_t off = (size_t)k * ch * BD_ + (size_t)b * D_ + d0;
  const float* xp = x + off;
  float*       op = out + off;
#pragma unroll 4
  for (int j = 0; j < ch; ++j) {
    float4 xv = *(const float4*)(xp + (size_t)j * BD_);
    float xa[4] = {xv.x, xv.y, xv.z, xv.w};
    float4 res;
    float* ra = &res.x;
#pragma unroll
    for (int q = 0; q < 4; ++q) {
      float nr = fmaf(cr[q], hr[q], fmaf(-ci[q], hi[q], xa[q]));
      float ni = fmaf(cr[q], hi[q], ci[q] * hr[q]);
      hr[q] = nr; hi[q] = ni;
      ra[q] = nr * xa[q];
    }
    *(float4*)(op + (size_t)j * BD_) = res;
  }
}

// ------------------------------------------------------------- fallback ----
// ws-free fully sequential per-column scan (used only if ws_size is tiny).
__global__ __launch_bounds__(256) void sc_full(
    const float* __restrict__ x,
    const float* __restrict__ lmlg,
    const float* __restrict__ theta,
    const float* __restrict__ init,
    float* __restrict__ out) {
  const int idx = blockIdx.x * 256 + threadIdx.x;   // column b*D+d
  const int d   = idx & (D_ - 1);
  float g  = expf(-expf(lmlg[d]));
  float cr = g * cosf(theta[d]), ci = g * sinf(theta[d]);
  float hr = init[d], hi = 0.f;
  const float* xp = x + idx;
  float*       op = out + idx;
  for (int n = 0; n < L_; ++n) {
    float xv = xp[(size_t)n * BD_];
    float nr = fmaf(cr, hr, fmaf(-ci, hi, xv));
    float ni = fmaf(cr, hi, ci * hr);
    hr = nr; hi = ni;
    op[(size_t)n * BD_] = nr * xv;
  }
}

// ---------------------------------------------------------------------------
extern "C" void kernel_launch(void* const* d_in, const int* in_sizes, int n_in,
                              void* d_out, int out_size, void* d_ws, size_t ws_size,
                              hipStream_t stream) {
  const float* x     = (const float*)d_in[0];
  const float* lmlg  = (const float*)d_in[1];
  const float* theta = (const float*)d_in[2];
  const float* init  = (const float*)d_in[3];
  float*  out = (float*)d_out;
  float2* ws  = (float2*)d_ws;

  // Largest pow2 chunk count that fits in ws: nc rows of BD_ float2s.
  const size_t row_bytes = (size_t)BD_ * sizeof(float2);   // 32 KiB
  int nc = 128;
  while (nc > 1 && (size_t)nc * row_bytes > ws_size) nc >>= 1;

  if (nc >= 2 && (size_t)nc * row_bytes <= ws_size) {
    const int ch = L_ / nc;
    sc_phase1<<<nc * B_, 256, 0, stream>>>(x, lmlg, theta, ws, ch);
    sc_phase2<<<BD_ / 256, 256, 0, stream>>>(lmlg, theta, init, ws, nc, (float)ch);
    sc_phase3<<<nc * B_, 256, 0, stream>>>(x, lmlg, theta, ws, out, ch);
  } else {
    sc_full<<<BD_ / 256, 256, 0, stream>>>(x, lmlg, theta, init, out);
  }
}

// Round 4
// 148.942 us; speedup vs baseline: 1.0727x; 1.0727x over previous
//
#include <hip/hip_runtime.h>

// SpiralConv conv block: per-channel complex first-order recurrence
//   h[n] = c*h[n-1] + x[n],  h[-1] = last_conv_init[d],  out = Re(h)*x
// with c_d = exp(-exp(lmlg_d)) * e^{i*theta_d}.
//
// R4: two-dispatch chunked scan. K1 writes per-chunk summaries (4 MiB,
// fits in one XCD L2). K2 blocks recompute their own carry by scanning
// the summary prefix from L2/L3 (avg 0.5 MiB, ~1 us), then replay the
// recurrence over their x chunk and write out. No dedicated carry pass
// (R2's phase2 ran on 16 CUs), no cooperative launch (R3 failed to launch).

#define L_  4096
#define B_  4
#define D_  1024
#define BD_ (B_ * D_)      // 4096 floats per time step

// ---------------------------------------------------------------- K1 -------
// One block per (chunk k, batch b); 256 threads x 4 channels = D.
// Chunk summary s = sum_j c^{ch-1-j} x[j]  (recurrence from 0 state).
__global__ __launch_bounds__(256) void sc_sum(
    const float* __restrict__ x,
    const float* __restrict__ lmlg,
    const float* __restrict__ theta,
    float2* __restrict__ ws, int ch) {
  const int t  = threadIdx.x;
  const int k  = blockIdx.x / B_;
  const int b  = blockIdx.x % B_;
  const int d0 = t * 4;

  float4 lg = *(const float4*)(lmlg + d0);
  float4 th = *(const float4*)(theta + d0);
  float cr[4], ci[4], sr[4] = {0.f,0.f,0.f,0.f}, si[4] = {0.f,0.f,0.f,0.f};
  {
    float g0 = expf(-expf(lg.x)), g1 = expf(-expf(lg.y));
    float g2 = expf(-expf(lg.z)), g3 = expf(-expf(lg.w));
    cr[0] = g0 * cosf(th.x); ci[0] = g0 * sinf(th.x);
    cr[1] = g1 * cosf(th.y); ci[1] = g1 * sinf(th.y);
    cr[2] = g2 * cosf(th.z); ci[2] = g2 * sinf(th.z);
    cr[3] = g3 * cosf(th.w); ci[3] = g3 * sinf(th.w);
  }

  const float* xp = x + (size_t)k * ch * BD_ + (size_t)b * D_ + d0;
#pragma unroll 4
  for (int j = 0; j < ch; ++j) {
    float4 xv = *(const float4*)(xp + (size_t)j * BD_);
    float xa[4] = {xv.x, xv.y, xv.z, xv.w};
#pragma unroll
    for (int q = 0; q < 4; ++q) {
      float nr = fmaf(cr[q], sr[q], fmaf(-ci[q], si[q], xa[q]));
      float ni = fmaf(cr[q], si[q], ci[q] * sr[q]);
      sr[q] = nr; si[q] = ni;
    }
  }

  float2* wp = ws + (size_t)(k * B_ + b) * D_ + d0;
  wp[0] = make_float2(sr[0], si[0]);
  wp[1] = make_float2(sr[1], si[1]);
  wp[2] = make_float2(sr[2], si[2]);
  wp[3] = make_float2(sr[3], si[3]);
}

// ---------------------------------------------------------------- K2 -------
// One block per (chunk k, batch b). Prefix-scan summaries 0..k-1 (L2-hot,
// 4 MiB total buffer) to get the carry into chunk k, then replay the
// per-step recurrence over x and write out = Re(h)*x.
__global__ __launch_bounds__(256) void sc_out(
    const float* __restrict__ x,
    const float* __restrict__ lmlg,
    const float* __restrict__ theta,
    const float* __restrict__ init,
    const float2* __restrict__ ws,
    float* __restrict__ out, int ch) {
  const int t  = threadIdx.x;
  const int k  = blockIdx.x / B_;
  const int b  = blockIdx.x % B_;
  const int d0 = t * 4;

  float4 lg = *(const float4*)(lmlg + d0);
  float4 th = *(const float4*)(theta + d0);
  float cr[4], ci[4];
  {
    float g0 = expf(-expf(lg.x)), g1 = expf(-expf(lg.y));
    float g2 = expf(-expf(lg.z)), g3 = expf(-expf(lg.w));
    cr[0] = g0 * cosf(th.x); ci[0] = g0 * sinf(th.x);
    cr[1] = g1 * cosf(th.y); ci[1] = g1 * sinf(th.y);
    cr[2] = g2 * cosf(th.z); ci[2] = g2 * sinf(th.z);
    cr[3] = g3 * cosf(th.w); ci[3] = g3 * sinf(th.w);
  }

  // jump factor C = c^ch  (computed from params, matches R2 numerics)
  const float chf = (float)ch;
  float Cr[4], Ci[4];
  {
    float e0 = expf(lg.x), e1 = expf(lg.y), e2 = expf(lg.z), e3 = expf(lg.w);
    float g0 = expf(-e0 * chf), g1 = expf(-e1 * chf);
    float g2 = expf(-e2 * chf), g3 = expf(-e3 * chf);
    Cr[0] = g0 * cosf(th.x * chf); Ci[0] = g0 * sinf(th.x * chf);
    Cr[1] = g1 * cosf(th.y * chf); Ci[1] = g1 * sinf(th.y * chf);
    Cr[2] = g2 * cosf(th.z * chf); Ci[2] = g2 * sinf(th.z * chf);
    Cr[3] = g3 * cosf(th.w * chf); Ci[3] = g3 * sinf(th.w * chf);
  }

  // carry into chunk k: h = init; for kk<k: h = C*h + s[kk]
  float4 iv = *(const float4*)(init + d0);
  float hr[4] = {iv.x, iv.y, iv.z, iv.w};
  float hi[4] = {0.f, 0.f, 0.f, 0.f};
  for (int kk = 0; kk < k; ++kk) {
    const float2* sp = ws + (size_t)(kk * B_ + b) * D_ + d0;
    float2 s0 = sp[0], s1 = sp[1], s2 = sp[2], s3 = sp[3];
    float sxr[4] = {s0.x, s1.x, s2.x, s3.x};
    float sxi[4] = {s0.y, s1.y, s2.y, s3.y};
#pragma unroll
    for (int q = 0; q < 4; ++q) {
      float nr = fmaf(Cr[q], hr[q], fmaf(-Ci[q], hi[q], sxr[q]));
      float ni = fmaf(Cr[q], hi[q], fmaf(Ci[q], hr[q], sxi[q]));
      hr[q] = nr; hi[q] = ni;
    }
  }

  // replay recurrence over this chunk, emit out = Re(h)*x
  const size_t off = (size_t)k * ch * BD_ + (size_t)b * D_ + d0;
  const float* xp = x + off;
  float*       op = out + off;
#pragma unroll 4
  for (int j = 0; j < ch; ++j) {
    float4 xv = *(const float4*)(xp + (size_t)j * BD_);
    float xa[4] = {xv.x, xv.y, xv.z, xv.w};
    float4 res; float* ra = &res.x;
#pragma unroll
    for (int q = 0; q < 4; ++q) {
      float nr = fmaf(cr[q], hr[q], fmaf(-ci[q], hi[q], xa[q]));
      float ni = fmaf(cr[q], hi[q], ci[q] * hr[q]);
      hr[q] = nr; hi[q] = ni;
      ra[q] = nr * xa[q];
    }
    *(float4*)(op + (size_t)j * BD_) = res;
  }
}

// ------------------------------------------------------------- fallback ----
// ws-free fully sequential per-column scan (used only if ws_size is tiny).
__global__ __launch_bounds__(256) void sc_full(
    const float* __restrict__ x, const float* __restrict__ lmlg,
    const float* __restrict__ theta, const float* __restrict__ init,
    float* __restrict__ out) {
  const int idx = blockIdx.x * 256 + threadIdx.x;   // column b*D+d
  const int d   = idx & (D_ - 1);
  float g = expf(-expf(lmlg[d]));
  float cr = g * cosf(theta[d]), ci = g * sinf(theta[d]);
  float hr = init[d], hi = 0.f;
  const float* xp = x + idx;
  float*       op = out + idx;
  for (int n = 0; n < L_; ++n) {
    float xv = xp[(size_t)n * BD_];
    float nr = fmaf(cr, hr, fmaf(-ci, hi, xv));
    float ni = fmaf(cr, hi, ci * hr);
    hr = nr; hi = ni;
    op[(size_t)n * BD_] = nr * xv;
  }
}

// ---------------------------------------------------------------------------
extern "C" void kernel_launch(void* const* d_in, const int* in_sizes, int n_in,
                              void* d_out, int out_size, void* d_ws, size_t ws_size,
                              hipStream_t stream) {
  const float* x     = (const float*)d_in[0];
  const float* lmlg  = (const float*)d_in[1];
  const float* theta = (const float*)d_in[2];
  const float* init  = (const float*)d_in[3];
  float*  out = (float*)d_out;
  float2* ws  = (float2*)d_ws;

  // largest pow2 chunk count whose summary rows fit in ws (row = 32 KiB)
  const size_t row_bytes = (size_t)BD_ * sizeof(float2);
  int nc = 128;
  while (nc > 1 && (size_t)nc * row_bytes > ws_size) nc >>= 1;

  if (nc >= 2 && (size_t)nc * row_bytes <= ws_size) {
    const int ch = L_ / nc;
    sc_sum<<<nc * B_, 256, 0, stream>>>(x, lmlg, theta, ws, ch);
    sc_out<<<nc * B_, 256, 0, stream>>>(x, lmlg, theta, init, ws, out, ch);
  } else {
    sc_full<<<BD_ / 256, 256, 0, stream>>>(x, lmlg, theta, init, out);
  }
}